// Round 7
// baseline (209.070 us; speedup 1.0000x reference)
//
#include <hip/hip_runtime.h>

// Camera back-projection R7: zero-LDS, zero-barrier, table-driven flat kernel.
//
// All structured variants (R4/R5/R6: LDS transpose + barriers, 50% occupancy)
// plateau at ~52-60us kernel time -- the phase-barrier structure itself is the
// limiter (compute and store phases serialize per block; latency-bound).
// R7 removes all structure: lanes span iz, so stores are directly contiguous
// (1KB per wave instr) with no transpose; no LDS, no __syncthreads.
//
// Tables (bit-exact, proven absmax 0.0 since R5) now pre-scaled byte offsets:
//   U[n][ix][iz] = 4*ui        | uok<<31   (u = fl*x/zc + 239.5, exact IEEE)
//   V[n][iy][iz] = 4*480*vi    | vok<<31
// gather byte offset = (U+V) & 0xFFFFF (max 921,596 < 2^20), valid = (U&V)<0.
// Epilogue: 1-128*min(|zc-d|,1/128) == max(fma(-128,|zc-d|,1),0) exactly
// (128*a is an exact power-of-2 scale, so fma == the reference's sub).
// Per output: ~8 VALU + 1 gather; U-row & zc loop-invariant per (n,ix) block.
//
// XCD swizzle: 2 depth images (1.8MB) per XCD -> gathers are L2 hits.
// __launch_bounds__(256,8): VGPR<=64 -> 8 blocks/CU resident (grid/CU = 8),
// 32 waves/CU of independent, barrier-free work.

#define RES  128
#define IMG  480
#define MAXN 32

__device__ unsigned g_U[MAXN * RES * RES];  // [n][ix][iz]
__device__ unsigned g_V[MAXN * RES * RES];  // [n][iy][iz]

__global__ __launch_bounds__(256) void cbp_tables(
    const float* __restrict__ fl, const float* __restrict__ cam_dist, int total)
{
    int t = blockIdx.x * 256 + threadIdx.x;
    if (t >= total) return;
    const int n = t >> 14;
    const int a = (t >> 7) & 127;   // ix for U, iy for V
    const int c = t & 127;          // iz for both
    const float flv = fl[n], cd = cam_dist[n];
    const float zc = cd - ((c + 0.5f) / 128.0f - 0.5f);
    {   // U (n, ix=a, iz=c) — same op order as reference
        const float x  = (a + 0.5f) / 128.0f - 0.5f;
        const float u  = (flv * x) / zc + 239.5f;            // exact IEEE div
        const int   ui = (int)fminf(fmaxf(rintf(u), 0.0f), 479.0f);
        const unsigned uok = (u >= 0.0f) && (u <= 479.0f);
        g_U[t] = (unsigned)(ui << 2) | (uok << 31);
    }
    {   // V (n, iy=a, iz=c)
        const float y  = (a + 0.5f) / 128.0f - 0.5f;
        const float v  = (flv * y) / zc + 239.5f;            // exact IEEE div
        const int   vi = (int)fminf(fmaxf(rintf(v), 0.0f), 479.0f);
        const unsigned vok = (v >= 0.0f) && (v <= 479.0f) && (zc > 0.0f);
        g_V[t] = (unsigned)((vi * IMG) << 2) | (vok << 31);
    }
}

__global__ __launch_bounds__(256, 8) void cbp_main(
    const float* __restrict__ depth, const float* __restrict__ cam_dist,
    float* __restrict__ out, int N)
{
    const int b = blockIdx.x;
    int n, ix;
    if (N == 16) {                  // XCD-local: 2 images per XCD
        const int xcd = b & 7, i = b >> 3;
        n = xcd * 2 + (i >> 7); ix = i & 127;
    } else { n = b >> 7; ix = b & 127; }

    const int l   = threadIdx.x & 63;
    const int w   = threadIdx.x >> 6;
    const int iz0 = (l & 31) << 2;      // iz quad
    const int iyh = l >> 5;             // 2 iy rows per wave -> 1KB store/instr

    const float cd = cam_dist[n];
    float zc[4];
#pragma unroll
    for (int j = 0; j < 4; ++j)
        zc[j] = cd - ((iz0 + j + 0.5f) / 128.0f - 0.5f);   // exact, loop-invariant

    const uint4 pu4 = *(const uint4*)&g_U[(((n << 7) + ix) << 7) + iz0]; // invariant
    const unsigned pua[4] = {pu4.x, pu4.y, pu4.z, pu4.w};
    const unsigned* __restrict__ Vn = &g_V[n << 14];
    const char* __restrict__ dbase = (const char*)(depth + (size_t)n * (IMG * IMG));
    float* __restrict__ obase = out + ((size_t)((n << 7) + ix) << 14);

#pragma unroll 2
    for (int it = 0; it < 16; ++it) {
        const int iy = it * 8 + w * 2 + iyh;
        const uint4 pv4 = *(const uint4*)&Vn[(iy << 7) + iz0];   // 1KB coalesced
        const unsigned pva[4] = {pv4.x, pv4.y, pv4.z, pv4.w};
        float4 r; float* rp = &r.x;
#pragma unroll
        for (int j = 0; j < 4; ++j) {
            const unsigned voff = (pua[j] + pva[j]) & 0xFFFFFu;  // byte offset
            const float d = *(const float*)(dbase + voff);       // L2-hot gather
            const bool ok = ((int)(pua[j] & pva[j]) < 0) && (d > 0.0f);
            const float val = fmaxf(fmaf(-128.0f, fabsf(zc[j] - d), 1.0f), 0.0f);
            rp[j] = ok ? val : 0.0f;
        }
        *(float4*)&obase[(iy << 7) + iz0] = r;   // 1KB contiguous per wave instr
    }
}

extern "C" void kernel_launch(void* const* d_in, const int* in_sizes, int n_in,
                              void* d_out, int out_size, void* d_ws, size_t ws_size,
                              hipStream_t stream) {
    const float* depth = (const float*)d_in[0];
    const float* fl    = (const float*)d_in[1];
    const float* cd    = (const float*)d_in[2];
    float* out         = (float*)d_out;

    const int N = in_sizes[1];                     // fl is (N,1)
    const int tab_total = N * RES * RES;
    cbp_tables<<<(tab_total + 255) / 256, 256, 0, stream>>>(fl, cd, tab_total);

    cbp_main<<<N * RES, 256, 0, stream>>>(depth, cd, out, N);
}

// Round 8
// 160.289 us; speedup vs baseline: 1.3043x; 1.3043x over previous
//
#include <hip/hip_runtime.h>

// Camera back-projection R8: R6 geometry + LDS-staged tables + full occupancy.
//
// Measured chain: gathers with lanes along iz splatter ~40-60 lines/instr
// (R1 64us, R7 94us w/ counters); lanes along ix ride image rows (~4-8
// lines/instr) but need an LDS transpose for iz-contiguous stores (R4/5/6,
// 52-60us). R8 keeps the good geometry and fixes R6's three leaks:
//   1. U table staged in LDS (R5/R6 did a strided GLOBAL U load per element
//      = 33.5M extra gathers).
//   2. Pre-scaled packing: U[n][ix][iz] = ui<<2 | uok<<15 (ushort),
//      V[n][iy][iz] = vi*1920 | vok<<31 (uint). Gather byte offset =
//      ((U&0x7FFF)+V)&0xFFFFF (2 VALU); valid = sign(V & (U<<16)).
//      d>0 test dropped: zc in [1.70,2.70] => d<=0 gives |zc-d|>1/128 =>
//      max(fma(-128,|zc-d|,1),0) = 0 exactly, same as the reference's trunc
//      path. Epilogue = fma+max (exact: 128*x is a pow2 scale).
//   3. iz chunked by 32: LDS = 16.1KB -> 8 blocks/CU = 32 waves/CU (the
//      phase barriers that flattened R3/R6 now overlap across 8 blocks).
// All LDS strides at the b128 conflict floor: tile 36, U 136, V 132.
// Stores: 8 full 128B lines per wave instr. XCD swizzle: 2 images/XCD in L2.
//
// Numerics: tables use exact IEEE '/' + rintf half-to-even, same op order as
// the reference (absmax 0.0 in every round since R1).

#define RES  128
#define IMG  480
#define MAXN 32
#define TS   36     // result tile row stride (floats)
#define US   136    // U slab row stride (ushorts); 136*2=272 (16B-mult)
#define VS   132    // V slab row stride (uints);   132*4=528 (16B-mult)

__device__ unsigned short g_U[MAXN * RES * RES];  // [n][ix][iz]
__device__ unsigned       g_V[MAXN * RES * RES];  // [n][iy][iz]

__global__ __launch_bounds__(256) void cbp_tables(
    const float* __restrict__ fl, const float* __restrict__ cam_dist, int total)
{
    int t = blockIdx.x * 256 + threadIdx.x;
    if (t >= total) return;
    const int n = t >> 14;
    const int a = (t >> 7) & 127;   // ix for U, iy for V
    const int c = t & 127;          // iz for both
    const float flv = fl[n], cd = cam_dist[n];
    const float zc = cd - ((c + 0.5f) / 128.0f - 0.5f);
    {   // U (n, ix=a, iz=c) — same op order as reference
        const float x  = (a + 0.5f) / 128.0f - 0.5f;
        const float u  = (flv * x) / zc + 239.5f;            // exact IEEE div
        const int   ui = (int)fminf(fmaxf(rintf(u), 0.0f), 479.0f);
        const unsigned uok = (u >= 0.0f) && (u <= 479.0f);
        g_U[t] = (unsigned short)((ui << 2) | (uok << 15));
    }
    {   // V (n, iy=a, iz=c)
        const float y  = (a + 0.5f) / 128.0f - 0.5f;
        const float v  = (flv * y) / zc + 239.5f;            // exact IEEE div
        const int   vi = (int)fminf(fmaxf(rintf(v), 0.0f), 479.0f);
        const unsigned vok = (v >= 0.0f) && (v <= 479.0f) && (zc > 0.0f);
        g_V[t] = (unsigned)(vi * (IMG * 4)) | (vok << 31);   // vi*1920 < 2^20
    }
}

__global__ __launch_bounds__(256, 8) void cbp_main(
    const float* __restrict__ depth, const float* __restrict__ cam_dist,
    float* __restrict__ out, int N)
{
    __shared__ __align__(16) float          s_tile[64 * TS];  // 9216 B
    __shared__ __align__(16) unsigned short s_U[16 * US];     // 4352 B
    __shared__ __align__(16) unsigned       s_V[4 * VS];      // 2112 B
    __shared__ __align__(16) float          s_zc[RES];        //  512 B

    const int b = blockIdx.x;
    int n, r;
    if (N == 16) {                  // XCD-local: 2 images per XCD
        const int xcd = b & 7, i = b >> 3;
        n = xcd * 2 + (i >> 8);
        r = i & 255;
    } else { n = b >> 8; r = b & 255; }
    const int ixg = r & 7;          // 16-ix group (0..7)
    const int iyg = r >> 3;         // 4-iy group  (0..31)
    const int l   = threadIdx.x;
    const float cd = cam_dist[n];

    // ---- stage tables into LDS (coalesced, one-time) ----
    {   // U slab: 16 ix x 128 iz ushorts
        const int row = l >> 4, seg = l & 15;
        *(uint4*)&s_U[row * US + seg * 8] =
            *(const uint4*)&g_U[(n << 14) + ((ixg * 16 + row) << 7) + seg * 8];
        // V slab: 4 iy x 128 iz uints (512 consecutive)
        const unsigned* __restrict__ gv = &g_V[(n << 14) + ((iyg * 4) << 7)];
        s_V[((l >> 7)) * VS + (l & 127)]            = gv[l];
        s_V[((l + 256) >> 7) * VS + (l & 127)]      = gv[l + 256];
        if (l < 128) s_zc[l] = cd - ((l + 0.5f) / 128.0f - 0.5f);
    }
    __syncthreads();

    const int ix_l = l & 15, iy_l = (l >> 4) & 3, w = l >> 6;
    const int trow = ix_l * 4 + iy_l;
    const char* __restrict__ dbase = (const char*)(depth + (size_t)n * (IMG * IMG));
    const size_t obase = ((size_t)((n << 7) + ixg * 16) << 7 | (iyg * 4)) << 7;

    for (int c = 0; c < 4; ++c) {
        // ---- compute: lanes = 16 ix x 4 iy, iz wave-uniform per instr ----
#pragma unroll
        for (int g = 0; g < 2; ++g) {
            const int jq  = w * 2 + g;          // iz quad within chunk (0..7)
            const int izc = c * 32 + jq * 4;    // global iz of quad
            const ushort4 pu4 = *(const ushort4*)&s_U[ix_l * US + izc];
            const uint4   pv4 = *(const uint4*)&s_V[iy_l * VS + izc];
            const float4  z4  = *(const float4*)&s_zc[izc];
            const unsigned pua[4] = {pu4.x, pu4.y, pu4.z, pu4.w};
            const unsigned pva[4] = {pv4.x, pv4.y, pv4.z, pv4.w};
            const float    zca[4] = {z4.x, z4.y, z4.z, z4.w};
            float4 rr; float* rp = &rr.x;
#pragma unroll
            for (int j = 0; j < 4; ++j) {
                const unsigned off = ((pua[j] & 0x7FFFu) + pva[j]) & 0xFFFFFu;
                const float d  = *(const float*)(dbase + off);   // L2-hot gather
                const bool ok  = (int)(pva[j] & (pua[j] << 16)) < 0;
                const float v  = fmaxf(fmaf(-128.0f, fabsf(zca[j] - d), 1.0f), 0.0f);
                rp[j] = ok ? v : 0.0f;
            }
            *(float4*)&s_tile[trow * TS + jq * 4] = rr;   // b128, bank floor
        }
        __syncthreads();

        // ---- store: 2 float4/thread; wave instr = 8 full 128B lines ----
#pragma unroll
        for (int s = 0; s < 2; ++s) {
            const int f  = l + 256 * s;          // 0..511
            const int rw = f >> 3, q = f & 7;
            const float4 val = *(const float4*)&s_tile[rw * TS + q * 4];
            const int ix2 = rw >> 2, iy2 = rw & 3;
            *(float4*)&out[obase + ((size_t)ix2 << 14) + (iy2 << 7) + c * 32 + q * 4] = val;
        }
        __syncthreads();
    }
}

extern "C" void kernel_launch(void* const* d_in, const int* in_sizes, int n_in,
                              void* d_out, int out_size, void* d_ws, size_t ws_size,
                              hipStream_t stream) {
    const float* depth = (const float*)d_in[0];
    const float* fl    = (const float*)d_in[1];
    const float* cd    = (const float*)d_in[2];
    float* out         = (float*)d_out;

    const int N = in_sizes[1];                     // fl is (N,1)
    const int tab_total = N * RES * RES;
    cbp_tables<<<(tab_total + 255) / 256, 256, 0, stream>>>(fl, cd, tab_total);

    cbp_main<<<N * 256, 256, 0, stream>>>(depth, cd, out, N);
}